// Round 5
// baseline (1544.173 us; speedup 1.0000x reference)
//
#include <hip/hip_runtime.h>
#include <cstdint>
#include <cstddef>

typedef __bf16 bf16_t;
typedef __bf16 bf16x8 __attribute__((ext_vector_type(8)));
typedef float f32x4 __attribute__((ext_vector_type(4)));

#define GLOBAL_AS __attribute__((address_space(1)))
#define LDS_AS    __attribute__((address_space(3)))

__device__ __forceinline__ void glds16(const void* g, void* l) {
    __builtin_amdgcn_global_load_lds((const GLOBAL_AS void*)g, (LDS_AS void*)l, 16, 0, 0);
}

// ---------------- conversions ----------------
__global__ void conv_k(const float* __restrict__ in, bf16_t* __restrict__ out, int n8) {
    int id = blockIdx.x * 256 + threadIdx.x;
    if (id >= n8) return;
    const float4* p = (const float4*)in;
    float4 a = p[2 * id], b = p[2 * id + 1];
    bf16x8 o;
    o[0] = (bf16_t)a.x; o[1] = (bf16_t)a.y; o[2] = (bf16_t)a.z; o[3] = (bf16_t)a.w;
    o[4] = (bf16_t)b.x; o[5] = (bf16_t)b.y; o[6] = (bf16_t)b.z; o[7] = (bf16_t)b.w;
    *(bf16x8*)(out + (size_t)id * 8) = o;
}

// x fp32 -> cols 0..127 of interleaved ha[N][256]
__global__ void conv_x_k(const float* __restrict__ in, bf16_t* __restrict__ ha, int n8) {
    int id = blockIdx.x * 256 + threadIdx.x;
    if (id >= n8) return;
    const float4* p = (const float4*)in;
    float4 a = p[2 * id], b = p[2 * id + 1];
    bf16x8 o;
    o[0] = (bf16_t)a.x; o[1] = (bf16_t)a.y; o[2] = (bf16_t)a.z; o[3] = (bf16_t)a.w;
    o[4] = (bf16_t)b.x; o[5] = (bf16_t)b.y; o[6] = (bf16_t)b.z; o[7] = (bf16_t)b.w;
    int row = id >> 4, ch = id & 15;
    *(bf16x8*)(ha + (size_t)row * 256 + ch * 8) = o;
}

// ---------------- merged weight: Wc = w1 @ W0, bcomb = w1 @ lin_b ----------------
__global__ void wcomb_k(const float* __restrict__ w1, const float* __restrict__ lin_w,
                        const float* __restrict__ lin_b, const float* __restrict__ eps_p,
                        bf16_t* __restrict__ wc, float* __restrict__ bcomb) {
    __shared__ float red[256];
    int c = blockIdx.x, t = threadIdx.x;
    const float* w1row = w1 + c * 256;
    float onepe = 1.f + *eps_p;
    float v;
    if (t < 128) {
        float acc = 0.f;
        for (int j = 0; j < 256; j++) acc += w1row[j] * lin_w[j * 128 + t];
        v = acc + onepe * (w1row[t] + w1row[t + 128]);
    } else {
        int m = t - 128;
        v = w1row[m] + w1row[t];
    }
    wc[c * 256 + t] = (bf16_t)v;
    red[t] = w1row[t] * lin_b[t];
    __syncthreads();
    for (int off = 128; off > 0; off >>= 1) {
        if (t < off) red[t] += red[t + off];
        __syncthreads();
    }
    if (t == 0) bcomb[c] = red[0];
}

// ---------------- edge-index dtype detection ----------------
__global__ void detect_k(const int* __restrict__ ei, int* __restrict__ flag) {
    int v = ei[2 * threadIdx.x + 1];
    if (v != 0) atomicOr(flag, 1);   // 1 => int32 layout
}

// ---------------- bucket sort of edges (bucket = dst >> 7, 128 nodes/bucket) ----------------
#define CHUNK 8192

__global__ __launch_bounds__(256) void bhist_k(const void* __restrict__ ei, const int* __restrict__ flag,
                                               int E, int* __restrict__ bcnt) {
    __shared__ int cnt[1024];
    int t = threadIdx.x;
    for (int b = t; b < 1024; b += 256) cnt[b] = 0;
    __syncthreads();
    int base = blockIdx.x * CHUNK;
    int i32 = *flag;
#pragma unroll 4
    for (int i = 0; i < CHUNK / 256; i++) {
        int e = base + t + 256 * i;
        if (e < E) {
            int dst = i32 ? ((const int*)ei)[e] : (int)((const long long*)ei)[e];
            atomicAdd(&cnt[dst >> 7], 1);
        }
    }
    __syncthreads();
    for (int b = t; b < 1024; b += 256)
        if (cnt[b]) atomicAdd(&bcnt[b], cnt[b]);
}

__global__ __launch_bounds__(1024) void bscan_k(const int* __restrict__ bcnt, int* __restrict__ boffs,
                                                int* __restrict__ gcur, int NBK, int E) {
    __shared__ int lds[1024];
    int t = threadIdx.x;
    int v = (t < NBK) ? bcnt[t] : 0;
    lds[t] = v;
    __syncthreads();
    for (int off = 1; off < 1024; off <<= 1) {
        int add = (t >= off) ? lds[t - off] : 0;
        __syncthreads();
        lds[t] += add;
        __syncthreads();
    }
    if (t < NBK) {
        int excl = lds[t] - v;
        boffs[t] = excl;
        gcur[t] = excl;
    }
    if (t == 0) boffs[NBK] = E;
}

// per-block multisplit: LDS hist -> LDS scan -> LDS placement -> coalesced flush
__global__ __launch_bounds__(256) void binfill_k(const void* __restrict__ ei, const int* __restrict__ flag,
                                                 int E, int NBK, int* __restrict__ gcur,
                                                 unsigned* __restrict__ pairs) {
    __shared__ int cnt[1024];
    __shared__ int pref[1024];
    __shared__ int cur[1024];
    __shared__ int gbase[1024];
    __shared__ int red[256];
    __shared__ unsigned slot[CHUNK];
    int t = threadIdx.x;
    int base = blockIdx.x * CHUNK;
    int chunk_n = E - base; if (chunk_n > CHUNK) chunk_n = CHUNK;
    int i32 = *flag;
    for (int b = t; b < 1024; b += 256) cnt[b] = 0;
    __syncthreads();
    // pass 1: hist
#pragma unroll 4
    for (int i = 0; i < CHUNK / 256; i++) {
        int e = base + t + 256 * i;
        if (e < E) {
            int dst = i32 ? ((const int*)ei)[e] : (int)((const long long*)ei)[e];
            atomicAdd(&cnt[dst >> 7], 1);
        }
    }
    __syncthreads();
    // scan cnt[1024] with 256 threads (4 per thread)
    int t4 = t * 4;
    int c0 = cnt[t4], c1 = cnt[t4 + 1], c2 = cnt[t4 + 2], c3 = cnt[t4 + 3];
    int s = c0 + c1 + c2 + c3;
    red[t] = s;
    __syncthreads();
    for (int off = 1; off < 256; off <<= 1) {
        int add = (t >= off) ? red[t - off] : 0;
        __syncthreads();
        red[t] += add;
        __syncthreads();
    }
    int run = red[t] - s;
    pref[t4] = run; cur[t4] = run; run += c0;
    pref[t4 + 1] = run; cur[t4 + 1] = run; run += c1;
    pref[t4 + 2] = run; cur[t4 + 2] = run; run += c2;
    pref[t4 + 3] = run; cur[t4 + 3] = run;
    __syncthreads();
    // pass 2: place into LDS slots
#pragma unroll 4
    for (int i = 0; i < CHUNK / 256; i++) {
        int e = base + t + 256 * i;
        if (e < E) {
            int dst, src;
            if (i32) { dst = ((const int*)ei)[e]; src = ((const int*)ei)[E + e]; }
            else     { dst = (int)((const long long*)ei)[e]; src = (int)((const long long*)ei)[E + e]; }
            int b = dst >> 7;
            int p = atomicAdd(&cur[b], 1);
            slot[p] = ((unsigned)(dst & 127) << 20) | (unsigned)src;
        }
    }
    __syncthreads();
    // per-bucket global base
    for (int b = t; b < 1024; b += 256) {
        int c = (b + 1 < 1024) ? (pref[b + 1] - pref[b]) : (chunk_n - pref[b]);
        if (b < NBK && c > 0) gbase[b] = atomicAdd(&gcur[b], c);
    }
    __syncthreads();
    // coalesced flush: consecutive lanes -> consecutive slots
    for (int i = t; i < chunk_n; i += 256) {
        int lo = 0, hi = NBK - 1;
        while (lo < hi) {
            int mid = (lo + hi + 1) >> 1;
            if (pref[mid] <= i) lo = mid; else hi = mid - 1;
        }
        pairs[gbase[lo] + (i - pref[lo])] = slot[i];
    }
}

// one block per bucket: LDS fp32 accumulator [128 nodes][128 ch], 16 edges in flight
__global__ __launch_bounds__(256) void bgather_k(bf16_t* __restrict__ ha, const int* __restrict__ boffs,
                                                 const unsigned* __restrict__ pairs, int N) {
    __shared__ float acc[128][132];
    int t = threadIdx.x;
    for (int i = t; i < 128 * 132; i += 256) ((float*)acc)[i] = 0.f;
    __syncthreads();
    int b = blockIdx.x;
    int s = boffs[b], e = boffs[b + 1];
    int w = t >> 6, lane = t & 63, g = lane >> 4, l15 = lane & 15;
    for (int i = s + w * 4 + g; i < e; i += 16) {
        unsigned u = pairs[i];
        int src = (int)(u & 0xFFFFFu);
        int dl = (int)(u >> 20);
        bf16x8 v = *(const bf16x8*)(ha + (size_t)src * 256 + l15 * 8);
#pragma unroll
        for (int j = 0; j < 8; j++) atomicAdd(&acc[dl][l15 * 8 + j], (float)v[j]);
    }
    __syncthreads();
    int node0 = b * 128;
    int r = t >> 1, half = t & 1;
    if (node0 + r < N) {
#pragma unroll
        for (int k2 = 0; k2 < 8; k2++) {
            bf16x8 o;
#pragma unroll
            for (int j = 0; j < 8; j++) o[j] = (bf16_t)acc[r][half * 64 + k2 * 8 + j];
            *(bf16x8*)(ha + (size_t)(node0 + r) * 256 + 128 + half * 64 + k2 * 8) = o;
        }
    }
}

// ---------------- LDS-staged K=256 MFMA GEMM ----------------
// W [NCOL][256] staged in LDS chunks [NCOL][BK=32] ([col][32] layout, conflict-free),
// double-buffered global_load_lds; A direct-from-global w/ register prefetch.
// mfma_f32_16x16x32_bf16 (m89): A lane A[l&15][(l>>4)*8+i]; B lane B[k][l&15];
// D reg i <-> out[row=(l>>4)*4+i][col=l&15].
template<int NCOL, bool BNIN, bool STATS, bool FINAL, bool BIAS>
__global__ __launch_bounds__(NCOL * 2, 4) void gemm_k(
    const bf16_t* __restrict__ A, const bf16_t* __restrict__ W,
    const float2* __restrict__ scsh2,
    float* __restrict__ sums, float* __restrict__ sqs,
    const float* __restrict__ bias,
    bf16_t* __restrict__ Obf, float* __restrict__ Of, int N)
{
    constexpr int NW = NCOL / 32;   // waves per block
    __shared__ __align__(16) bf16_t wl[2][NCOL * 32];
    __shared__ float2 ssl[BNIN ? 256 : 1];
    __shared__ float ps[STATS ? NW : 1][STATS ? 128 : 1];
    __shared__ float pq[STATS ? NW : 1][STATS ? 128 : 1];

    const int tid = threadIdx.x;
    if constexpr (BNIN) { if (tid < 256) ssl[tid] = scsh2[tid]; }
    const int lane = tid & 63, wid = tid >> 6;
    const int l15 = lane & 15, l4 = lane >> 4;
    const int wr = wid & 3, wc = wid >> 2;
    const int rows0 = blockIdx.x * 128 + wr * 32;
    int ra0 = rows0 + l15;      if (ra0 > N - 1) ra0 = N - 1;
    int ra1 = rows0 + 16 + l15; if (ra1 > N - 1) ra1 = N - 1;

    auto stage = [&](int buf, int c) {
#pragma unroll
        for (int s = 0; s < 2; s++) {
            int d = ((s * NW + wid) * 64 + lane) * 16;   // byte offset, wave-linear dest
            int col = d >> 6, koff = d & 63;
            glds16((const char*)W + (size_t)col * 512 + c * 64 + koff,
                   (char*)&wl[buf][0] + d);
        }
    };
    stage(0, 0);
    __syncthreads();

    f32x4 acc0[8], acc1[8];
#pragma unroll
    for (int i = 0; i < 8; i++) { acc0[i] = f32x4{0.f,0.f,0.f,0.f}; acc1[i] = f32x4{0.f,0.f,0.f,0.f}; }

    bf16x8 pa0 = *(const bf16x8*)(A + (size_t)ra0 * 256 + l4 * 8);
    bf16x8 pa1 = *(const bf16x8*)(A + (size_t)ra1 * 256 + l4 * 8);

    for (int c = 0; c < 8; c++) {
        const int buf = c & 1;
        if (c + 1 < 8) stage(buf ^ 1, c + 1);
        bf16x8 ca0 = pa0, ca1 = pa1;
        if (c + 1 < 8) {
            int kn = (c + 1) * 32 + l4 * 8;
            pa0 = *(const bf16x8*)(A + (size_t)ra0 * 256 + kn);
            pa1 = *(const bf16x8*)(A + (size_t)ra1 * 256 + kn);
        }
        if constexpr (BNIN) {
            const int k0 = c * 32 + l4 * 8;
            bf16x8 t0, t1;
#pragma unroll
            for (int i = 0; i < 8; i++) {
                float2 ss = ssl[k0 + i];
                float f0 = (float)ca0[i] * ss.x + ss.y; f0 = fmaxf(f0, 0.f);
                float f1 = (float)ca1[i] * ss.x + ss.y; f1 = fmaxf(f1, 0.f);
                t0[i] = (bf16_t)f0; t1[i] = (bf16_t)f1;
            }
            ca0 = t0; ca1 = t1;
        }
#pragma unroll
        for (int ot = 0; ot < 8; ot++) {
            int colw = wc * 128 + ot * 16 + l15;
            const bf16x8 b = *(const bf16x8*)((const char*)&wl[buf][0] + colw * 64 + l4 * 16);
            acc0[ot] = __builtin_amdgcn_mfma_f32_16x16x32_bf16(ca0, b, acc0[ot], 0, 0, 0);
            acc1[ot] = __builtin_amdgcn_mfma_f32_16x16x32_bf16(ca1, b, acc1[ot], 0, 0, 0);
        }
        __syncthreads();
    }

    const int rb0 = rows0 + l4 * 4, rb1 = rows0 + 16 + l4 * 4;
#pragma unroll
    for (int ot = 0; ot < 8; ot++) {
        int colw = wc * 128 + ot * 16 + l15;
        float s = 0.f, q = 0.f;
#pragma unroll
        for (int half = 0; half < 2; half++) {
            int rb = half ? rb1 : rb0;
            f32x4 av = half ? acc1[ot] : acc0[ot];
#pragma unroll
            for (int i = 0; i < 4; i++) {
                int r = rb + i;
                if constexpr (FINAL) {
                    if (r < N) Of[(size_t)r * NCOL + colw] = av[i] + bias[colw];
                } else {
                    float v = av[i];
                    if constexpr (BIAS) v += bias[colw];
                    bf16_t hv = (bf16_t)v;
                    if (r < N) Obf[(size_t)r * 256 + colw] = hv;
                    if constexpr (STATS) {
                        float vv = (r < N) ? (float)hv : 0.f;
                        s += vv; q += vv * vv;
                    }
                }
            }
        }
        if constexpr (STATS) {
            s += __shfl_xor(s, 16); s += __shfl_xor(s, 32);
            q += __shfl_xor(q, 16); q += __shfl_xor(q, 32);
            if (lane < 16) { ps[wid][ot * 16 + l15] = s; pq[wid][ot * 16 + l15] = q; }
        }
    }
    if constexpr (STATS) {
        __syncthreads();
        if (tid < 256) {
            int gq = (tid >> 7) * 4, cl = tid & 127;
            atomicAdd(&sums[tid], ps[gq][cl] + ps[gq + 1][cl] + ps[gq + 2][cl] + ps[gq + 3][cl]);
        } else {
            int u = tid - 256;
            int gq = (u >> 7) * 4, cl = u & 127;
            atomicAdd(&sqs[u], pq[gq][cl] + pq[gq + 1][cl] + pq[gq + 2][cl] + pq[gq + 3][cl]);
        }
    }
}

__global__ void finalize_k(const float* __restrict__ sum, const float* __restrict__ sq,
                           const float* __restrict__ g, const float* __restrict__ b,
                           float2* __restrict__ scsh2, float invN) {
    int t = threadIdx.x;
    float mean = sum[t] * invN;
    float var = sq[t] * invN - mean * mean;
    float s = g[t] * rsqrtf(var + 1e-5f);
    scsh2[t] = make_float2(s, b[t] - mean * s);
}

extern "C" void kernel_launch(void* const* d_in, const int* in_sizes, int n_in,
                              void* d_out, int out_size, void* d_ws, size_t ws_size,
                              hipStream_t stream)
{
    const int N = in_sizes[0] / 128;
    const int E = in_sizes[1] / 2;
    const float* x     = (const float*)d_in[0];
    const void*  ei    = d_in[1];
    const float* lin_w = (const float*)d_in[2];
    const float* lin_b = (const float*)d_in[3];
    const float* eps   = (const float*)d_in[4];
    const float* w1    = (const float*)d_in[5];
    const float* g1    = (const float*)d_in[6];
    const float* b1    = (const float*)d_in[7];
    const float* w2    = (const float*)d_in[8];
    const float* g2    = (const float*)d_in[9];
    const float* b2    = (const float*)d_in[10];
    const float* w3    = (const float*)d_in[11];
    const float* b3    = (const float*)d_in[12];
    float* out = (float*)d_out;

    char* ws = (char*)d_ws;
    size_t o = 0;
    auto alloc = [&](size_t bytes) -> char* {
        char* p = ws + o;
        o = (o + bytes + 255) & ~(size_t)255;
        return p;
    };
    bf16_t*   ha    = (bf16_t*)alloc((size_t)N * 256 * 2);  // [x | agg], later t2
    bf16_t*   hb    = (bf16_t*)alloc((size_t)N * 256 * 2);  // t1
    bf16_t*   wcb   = (bf16_t*)alloc((size_t)256 * 256 * 2);
    bf16_t*   w2b   = (bf16_t*)alloc((size_t)256 * 256 * 2);
    bf16_t*   w3b   = (bf16_t*)alloc((size_t)128 * 256 * 2);
    float*    bcomb = (float*)alloc(256 * 4);
    float*    stats = (float*)alloc(4 * 256 * 4);   // sum1, sq1, sum2, sq2
    float2*   scsh1 = (float2*)alloc(256 * 8);
    float2*   scsh2 = (float2*)alloc(256 * 8);
    int*      bcnt  = (int*)alloc(1024 * 4);
    int*      boffs = (int*)alloc(1025 * 4);
    int*      gcur  = (int*)alloc(1024 * 4);
    unsigned* pairs = (unsigned*)alloc((size_t)E * 4);
    int*      flag  = (int*)alloc(4);

    const int NBK = (N + 127) >> 7;

    hipMemsetAsync(bcnt, 0, 1024 * 4, stream);
    hipMemsetAsync(stats, 0, 4 * 256 * 4, stream);
    hipMemsetAsync(flag, 0, 4, stream);

    // conversions / weight prep
    int nx8 = N * 16;
    conv_x_k<<<(nx8 + 255) / 256, 256, 0, stream>>>(x, ha, nx8);
    wcomb_k<<<256, 256, 0, stream>>>(w1, lin_w, lin_b, eps, wcb, bcomb);
    conv_k<<<32, 256, 0, stream>>>(w2, w2b, 8192);
    conv_k<<<16, 256, 0, stream>>>(w3, w3b, 4096);

    // bucket sort of edges + LDS-accumulated gather
    const int nch = (E + CHUNK - 1) / CHUNK;
    detect_k<<<1, 256, 0, stream>>>((const int*)ei, flag);
    bhist_k<<<nch, 256, 0, stream>>>(ei, flag, E, bcnt);
    bscan_k<<<1, 1024, 0, stream>>>(bcnt, boffs, gcur, NBK, E);
    binfill_k<<<nch, 256, 0, stream>>>(ei, flag, E, NBK, gcur, pairs);
    bgather_k<<<NBK, 256, 0, stream>>>(ha, boffs, pairs, N);

    const int nb = (N + 127) / 128;
    // t1 = [x|agg] @ Wc^T + bcomb (+ BN1 stats)
    gemm_k<256, false, true, false, true><<<nb, 512, 0, stream>>>(
        ha, wcb, nullptr, stats + 0, stats + 256, bcomb, hb, nullptr, N);
    finalize_k<<<1, 256, 0, stream>>>(stats + 0, stats + 256, g1, b1, scsh1, 1.f / (float)N);
    // t2 = relu(BN1(t1))@w2^T (+ BN2 stats)
    gemm_k<256, true, true, false, false><<<nb, 512, 0, stream>>>(
        hb, w2b, scsh1, stats + 512, stats + 768, nullptr, ha, nullptr, N);
    finalize_k<<<1, 256, 0, stream>>>(stats + 512, stats + 768, g2, b2, scsh2, 1.f / (float)N);
    // out = relu(BN2(t2))@w3^T + b3
    gemm_k<128, true, false, true, true><<<nb, 256, 0, stream>>>(
        ha, w3b, scsh2, nullptr, nullptr, b3, nullptr, out, N);
}

// Round 6
// 296.874 us; speedup vs baseline: 5.2014x; 5.2014x over previous
//
#include <hip/hip_runtime.h>
#include <cstdint>
#include <cstddef>

typedef __bf16 bf16_t;
typedef __bf16 bf16x8 __attribute__((ext_vector_type(8)));
typedef float f32x4 __attribute__((ext_vector_type(4)));

#define GLOBAL_AS __attribute__((address_space(1)))
#define LDS_AS    __attribute__((address_space(3)))

__device__ __forceinline__ void glds16(const void* g, void* l) {
    __builtin_amdgcn_global_load_lds((const GLOBAL_AS void*)g, (LDS_AS void*)l, 16, 0, 0);
}

// ---------------- conversions ----------------
__global__ void conv_k(const float* __restrict__ in, bf16_t* __restrict__ out, int n8) {
    int id = blockIdx.x * 256 + threadIdx.x;
    if (id >= n8) return;
    const float4* p = (const float4*)in;
    float4 a = p[2 * id], b = p[2 * id + 1];
    bf16x8 o;
    o[0] = (bf16_t)a.x; o[1] = (bf16_t)a.y; o[2] = (bf16_t)a.z; o[3] = (bf16_t)a.w;
    o[4] = (bf16_t)b.x; o[5] = (bf16_t)b.y; o[6] = (bf16_t)b.z; o[7] = (bf16_t)b.w;
    *(bf16x8*)(out + (size_t)id * 8) = o;
}

// x fp32 -> cols 0..127 of interleaved ha[N][256]
__global__ void conv_x_k(const float* __restrict__ in, bf16_t* __restrict__ ha, int n8) {
    int id = blockIdx.x * 256 + threadIdx.x;
    if (id >= n8) return;
    const float4* p = (const float4*)in;
    float4 a = p[2 * id], b = p[2 * id + 1];
    bf16x8 o;
    o[0] = (bf16_t)a.x; o[1] = (bf16_t)a.y; o[2] = (bf16_t)a.z; o[3] = (bf16_t)a.w;
    o[4] = (bf16_t)b.x; o[5] = (bf16_t)b.y; o[6] = (bf16_t)b.z; o[7] = (bf16_t)b.w;
    int row = id >> 4, ch = id & 15;
    *(bf16x8*)(ha + (size_t)row * 256 + ch * 8) = o;
}

// ---------------- merged weight: Wc = w1 @ W0, bcomb = w1 @ lin_b ----------------
__global__ void wcomb_k(const float* __restrict__ w1, const float* __restrict__ lin_w,
                        const float* __restrict__ lin_b, const float* __restrict__ eps_p,
                        bf16_t* __restrict__ wc, float* __restrict__ bcomb) {
    __shared__ float red[256];
    int c = blockIdx.x, t = threadIdx.x;
    const float* w1row = w1 + c * 256;
    float onepe = 1.f + *eps_p;
    float v;
    if (t < 128) {
        float acc = 0.f;
        for (int j = 0; j < 256; j++) acc += w1row[j] * lin_w[j * 128 + t];
        v = acc + onepe * (w1row[t] + w1row[t + 128]);
    } else {
        int m = t - 128;
        v = w1row[m] + w1row[t];
    }
    wc[c * 256 + t] = (bf16_t)v;
    red[t] = w1row[t] * lin_b[t];
    __syncthreads();
    for (int off = 128; off > 0; off >>= 1) {
        if (t < off) red[t] += red[t + off];
        __syncthreads();
    }
    if (t == 0) bcomb[c] = red[0];
}

// ---------------- edge-index dtype detection ----------------
__global__ void detect_k(const int* __restrict__ ei, int* __restrict__ flag) {
    int v = ei[2 * threadIdx.x + 1];
    if (v != 0) atomicOr(flag, 1);   // 1 => int32 layout
}

// ---------------- bucket sort of edges (bucket = dst >> 7, 128 nodes/bucket) ----------------
#define CHUNK 8192

__global__ __launch_bounds__(256) void bhist_k(const void* __restrict__ ei, const int* __restrict__ flag,
                                               int E, int* __restrict__ bcnt) {
    __shared__ int cnt[1024];
    int t = threadIdx.x;
    for (int b = t; b < 1024; b += 256) cnt[b] = 0;
    __syncthreads();
    int base = blockIdx.x * CHUNK;
    int i32 = *flag;
#pragma unroll 4
    for (int i = 0; i < CHUNK / 256; i++) {
        int e = base + t + 256 * i;
        if (e < E) {
            int dst = i32 ? ((const int*)ei)[e] : (int)((const long long*)ei)[e];
            atomicAdd(&cnt[dst >> 7], 1);
        }
    }
    __syncthreads();
    for (int b = t; b < 1024; b += 256)
        if (cnt[b]) atomicAdd(&bcnt[b], cnt[b]);
}

__global__ __launch_bounds__(1024) void bscan_k(const int* __restrict__ bcnt, int* __restrict__ boffs,
                                                int* __restrict__ gcur, int* __restrict__ offs,
                                                int NBK, int N, int E) {
    __shared__ int lds[1024];
    int t = threadIdx.x;
    int v = (t < NBK) ? bcnt[t] : 0;
    lds[t] = v;
    __syncthreads();
    for (int off = 1; off < 1024; off <<= 1) {
        int add = (t >= off) ? lds[t - off] : 0;
        __syncthreads();
        lds[t] += add;
        __syncthreads();
    }
    if (t < NBK) {
        int excl = lds[t] - v;
        boffs[t] = excl;
        gcur[t] = excl;
    }
    if (t == 0) { boffs[NBK] = E; offs[N] = E; }
}

// per-block multisplit: LDS hist -> LDS scan -> LDS placement -> coalesced flush
__global__ __launch_bounds__(256) void binfill_k(const void* __restrict__ ei, const int* __restrict__ flag,
                                                 int E, int NBK, int* __restrict__ gcur,
                                                 unsigned* __restrict__ pairs) {
    __shared__ int cnt[1024];
    __shared__ int pref[1024];
    __shared__ int cur[1024];
    __shared__ int gbase[1024];
    __shared__ int red[256];
    __shared__ unsigned slot[CHUNK];
    int t = threadIdx.x;
    int base = blockIdx.x * CHUNK;
    int chunk_n = E - base; if (chunk_n > CHUNK) chunk_n = CHUNK;
    int i32 = *flag;
    for (int b = t; b < 1024; b += 256) cnt[b] = 0;
    __syncthreads();
    // pass 1: hist
#pragma unroll 4
    for (int i = 0; i < CHUNK / 256; i++) {
        int e = base + t + 256 * i;
        if (e < E) {
            int dst = i32 ? ((const int*)ei)[e] : (int)((const long long*)ei)[e];
            atomicAdd(&cnt[dst >> 7], 1);
        }
    }
    __syncthreads();
    // scan cnt[1024] with 256 threads (4 per thread)
    int t4 = t * 4;
    int c0 = cnt[t4], c1 = cnt[t4 + 1], c2 = cnt[t4 + 2], c3 = cnt[t4 + 3];
    int s = c0 + c1 + c2 + c3;
    red[t] = s;
    __syncthreads();
    for (int off = 1; off < 256; off <<= 1) {
        int add = (t >= off) ? red[t - off] : 0;
        __syncthreads();
        red[t] += add;
        __syncthreads();
    }
    int run = red[t] - s;
    pref[t4] = run; cur[t4] = run; run += c0;
    pref[t4 + 1] = run; cur[t4 + 1] = run; run += c1;
    pref[t4 + 2] = run; cur[t4 + 2] = run; run += c2;
    pref[t4 + 3] = run; cur[t4 + 3] = run;
    __syncthreads();
    // pass 2: place into LDS slots
#pragma unroll 4
    for (int i = 0; i < CHUNK / 256; i++) {
        int e = base + t + 256 * i;
        if (e < E) {
            int dst, src;
            if (i32) { dst = ((const int*)ei)[e]; src = ((const int*)ei)[E + e]; }
            else     { dst = (int)((const long long*)ei)[e]; src = (int)((const long long*)ei)[E + e]; }
            int b = dst >> 7;
            int p = atomicAdd(&cur[b], 1);
            slot[p] = ((unsigned)(dst & 127) << 20) | (unsigned)src;
        }
    }
    __syncthreads();
    // per-bucket global base
    for (int b = t; b < 1024; b += 256) {
        int c = (b + 1 < 1024) ? (pref[b + 1] - pref[b]) : (chunk_n - pref[b]);
        if (b < NBK && c > 0) gbase[b] = atomicAdd(&gcur[b], c);
    }
    __syncthreads();
    // coalesced flush: consecutive lanes -> consecutive slots
    for (int i = t; i < chunk_n; i += 256) {
        int lo = 0, hi = NBK - 1;
        while (lo < hi) {
            int mid = (lo + hi + 1) >> 1;
            if (pref[mid] <= i) lo = mid; else hi = mid - 1;
        }
        pairs[gbase[lo] + (i - pref[lo])] = slot[i];
    }
}

// level-2 counting sort: one block per bucket -> per-node CSR + offs
__global__ __launch_bounds__(256) void bsort2_k(const unsigned* __restrict__ pairs,
                                                const int* __restrict__ boffs,
                                                int* __restrict__ offs,
                                                int* __restrict__ csr, int N) {
    __shared__ int cnt[128], pref[128], cur[128];
    int t = threadIdx.x;
    int b = blockIdx.x;
    int s = boffs[b], e = boffs[b + 1];
    if (t < 128) cnt[t] = 0;
    __syncthreads();
    for (int i = s + t; i < e; i += 256)
        atomicAdd(&cnt[pairs[i] >> 20], 1);
    __syncthreads();
    if (t < 128) pref[t] = cnt[t];
    __syncthreads();
    for (int off = 1; off < 128; off <<= 1) {
        int v = 0;
        if (t < 128 && t >= off) v = pref[t - off];
        __syncthreads();
        if (t < 128) pref[t] += v;
        __syncthreads();
    }
    if (t < 128) {
        int ex = pref[t] - cnt[t];      // exclusive prefix
        cur[t] = ex;
        int node = b * 128 + t;
        if (node < N) offs[node] = s + ex;
    }
    __syncthreads();
    for (int i = s + t; i < e; i += 256) {
        unsigned u = pairs[i];
        int dl = (int)(u >> 20);
        int p = atomicAdd(&cur[dl], 1);
        csr[s + p] = (int)(u & 0xFFFFFu);
    }
}

// one wave per node; 4 neighbor rows in flight, 16 lanes x 16B (bf16x8) per row
__global__ __launch_bounds__(256) void gather_k(bf16_t* __restrict__ ha, const int* __restrict__ offs,
                                                const int* __restrict__ csr, int N) {
    int w = (blockIdx.x * 256 + threadIdx.x) >> 6;
    if (w >= N) return;
    int lane = threadIdx.x & 63;
    int g = lane >> 4, l15 = lane & 15;
    int s = offs[w], e = offs[w + 1];
    float acc[8] = {0.f, 0.f, 0.f, 0.f, 0.f, 0.f, 0.f, 0.f};
    for (int i = s + g; i < e; i += 4) {
        int src = csr[i];
        bf16x8 v = *(const bf16x8*)(ha + (size_t)src * 256 + l15 * 8);
#pragma unroll
        for (int j = 0; j < 8; j++) acc[j] += (float)v[j];
    }
#pragma unroll
    for (int j = 0; j < 8; j++) {
        acc[j] += __shfl_xor(acc[j], 16);
        acc[j] += __shfl_xor(acc[j], 32);
    }
    if (g == 0) {
        bf16x8 o;
#pragma unroll
        for (int j = 0; j < 8; j++) o[j] = (bf16_t)acc[j];
        *(bf16x8*)(ha + (size_t)w * 256 + 128 + l15 * 8) = o;
    }
}

// ---------------- LDS-staged K=256 MFMA GEMM ----------------
// W [NCOL][256] staged in LDS chunks [NCOL][BK=32] ([col][32] layout, conflict-free),
// double-buffered global_load_lds; A direct-from-global w/ register prefetch.
// mfma_f32_16x16x32_bf16 (m89): A lane A[l&15][(l>>4)*8+i]; B lane B[k][l&15];
// D reg i <-> out[row=(l>>4)*4+i][col=l&15].
template<int NCOL, bool BNIN, bool STATS, bool FINAL, bool BIAS>
__global__ __launch_bounds__(NCOL * 2, 4) void gemm_k(
    const bf16_t* __restrict__ A, const bf16_t* __restrict__ W,
    const float2* __restrict__ scsh2,
    float* __restrict__ sums, float* __restrict__ sqs,
    const float* __restrict__ bias,
    bf16_t* __restrict__ Obf, float* __restrict__ Of, int N)
{
    constexpr int NW = NCOL / 32;   // waves per block
    __shared__ __align__(16) bf16_t wl[2][NCOL * 32];
    __shared__ float2 ssl[BNIN ? 256 : 1];
    __shared__ float ps[STATS ? NW : 1][STATS ? 128 : 1];
    __shared__ float pq[STATS ? NW : 1][STATS ? 128 : 1];

    const int tid = threadIdx.x;
    if constexpr (BNIN) { if (tid < 256) ssl[tid] = scsh2[tid]; }
    const int lane = tid & 63, wid = tid >> 6;
    const int l15 = lane & 15, l4 = lane >> 4;
    const int wr = wid & 3, wc = wid >> 2;
    const int rows0 = blockIdx.x * 128 + wr * 32;
    int ra0 = rows0 + l15;      if (ra0 > N - 1) ra0 = N - 1;
    int ra1 = rows0 + 16 + l15; if (ra1 > N - 1) ra1 = N - 1;

    auto stage = [&](int buf, int c) {
#pragma unroll
        for (int s = 0; s < 2; s++) {
            int d = ((s * NW + wid) * 64 + lane) * 16;   // byte offset, wave-linear dest
            int col = d >> 6, koff = d & 63;
            glds16((const char*)W + (size_t)col * 512 + c * 64 + koff,
                   (char*)&wl[buf][0] + d);
        }
    };
    stage(0, 0);
    __syncthreads();

    f32x4 acc0[8], acc1[8];
#pragma unroll
    for (int i = 0; i < 8; i++) { acc0[i] = f32x4{0.f,0.f,0.f,0.f}; acc1[i] = f32x4{0.f,0.f,0.f,0.f}; }

    bf16x8 pa0 = *(const bf16x8*)(A + (size_t)ra0 * 256 + l4 * 8);
    bf16x8 pa1 = *(const bf16x8*)(A + (size_t)ra1 * 256 + l4 * 8);

    for (int c = 0; c < 8; c++) {
        const int buf = c & 1;
        if (c + 1 < 8) stage(buf ^ 1, c + 1);
        bf16x8 ca0 = pa0, ca1 = pa1;
        if (c + 1 < 8) {
            int kn = (c + 1) * 32 + l4 * 8;
            pa0 = *(const bf16x8*)(A + (size_t)ra0 * 256 + kn);
            pa1 = *(const bf16x8*)(A + (size_t)ra1 * 256 + kn);
        }
        if constexpr (BNIN) {
            const int k0 = c * 32 + l4 * 8;
            bf16x8 t0, t1;
#pragma unroll
            for (int i = 0; i < 8; i++) {
                float2 ss = ssl[k0 + i];
                float f0 = (float)ca0[i] * ss.x + ss.y; f0 = fmaxf(f0, 0.f);
                float f1 = (float)ca1[i] * ss.x + ss.y; f1 = fmaxf(f1, 0.f);
                t0[i] = (bf16_t)f0; t1[i] = (bf16_t)f1;
            }
            ca0 = t0; ca1 = t1;
        }
#pragma unroll
        for (int ot = 0; ot < 8; ot++) {
            int colw = wc * 128 + ot * 16 + l15;
            const bf16x8 b = *(const bf16x8*)((const char*)&wl[buf][0] + colw * 64 + l4 * 16);
            acc0[ot] = __builtin_amdgcn_mfma_f32_16x16x32_bf16(ca0, b, acc0[ot], 0, 0, 0);
            acc1[ot] = __builtin_amdgcn_mfma_f32_16x16x32_bf16(ca1, b, acc1[ot], 0, 0, 0);
        }
        __syncthreads();
    }

    const int rb0 = rows0 + l4 * 4, rb1 = rows0 + 16 + l4 * 4;
#pragma unroll
    for (int ot = 0; ot < 8; ot++) {
        int colw = wc * 128 + ot * 16 + l15;
        float s = 0.f, q = 0.f;
#pragma unroll
        for (int half = 0; half < 2; half++) {
            int rb = half ? rb1 : rb0;
            f32x4 av = half ? acc1[ot] : acc0[ot];
#pragma unroll
            for (int i = 0; i < 4; i++) {
                int r = rb + i;
                if constexpr (FINAL) {
                    if (r < N) Of[(size_t)r * NCOL + colw] = av[i] + bias[colw];
                } else {
                    float v = av[i];
                    if constexpr (BIAS) v += bias[colw];
                    bf16_t hv = (bf16_t)v;
                    if (r < N) Obf[(size_t)r * 256 + colw] = hv;
                    if constexpr (STATS) {
                        float vv = (r < N) ? (float)hv : 0.f;
                        s += vv; q += vv * vv;
                    }
                }
            }
        }
        if constexpr (STATS) {
            s += __shfl_xor(s, 16); s += __shfl_xor(s, 32);
            q += __shfl_xor(q, 16); q += __shfl_xor(q, 32);
            if (lane < 16) { ps[wid][ot * 16 + l15] = s; pq[wid][ot * 16 + l15] = q; }
        }
    }
    if constexpr (STATS) {
        __syncthreads();
        if (tid < 256) {
            int gq = (tid >> 7) * 4, cl = tid & 127;
            atomicAdd(&sums[tid], ps[gq][cl] + ps[gq + 1][cl] + ps[gq + 2][cl] + ps[gq + 3][cl]);
        } else {
            int u = tid - 256;
            int gq = (u >> 7) * 4, cl = u & 127;
            atomicAdd(&sqs[u], pq[gq][cl] + pq[gq + 1][cl] + pq[gq + 2][cl] + pq[gq + 3][cl]);
        }
    }
}

__global__ void finalize_k(const float* __restrict__ sum, const float* __restrict__ sq,
                           const float* __restrict__ g, const float* __restrict__ b,
                           float2* __restrict__ scsh2, float invN) {
    int t = threadIdx.x;
    float mean = sum[t] * invN;
    float var = sq[t] * invN - mean * mean;
    float s = g[t] * rsqrtf(var + 1e-5f);
    scsh2[t] = make_float2(s, b[t] - mean * s);
}

extern "C" void kernel_launch(void* const* d_in, const int* in_sizes, int n_in,
                              void* d_out, int out_size, void* d_ws, size_t ws_size,
                              hipStream_t stream)
{
    const int N = in_sizes[0] / 128;
    const int E = in_sizes[1] / 2;
    const float* x     = (const float*)d_in[0];
    const void*  ei    = d_in[1];
    const float* lin_w = (const float*)d_in[2];
    const float* lin_b = (const float*)d_in[3];
    const float* eps   = (const float*)d_in[4];
    const float* w1    = (const float*)d_in[5];
    const float* g1    = (const float*)d_in[6];
    const float* b1    = (const float*)d_in[7];
    const float* w2    = (const float*)d_in[8];
    const float* g2    = (const float*)d_in[9];
    const float* b2    = (const float*)d_in[10];
    const float* w3    = (const float*)d_in[11];
    const float* b3    = (const float*)d_in[12];
    float* out = (float*)d_out;

    char* ws = (char*)d_ws;
    size_t o = 0;
    auto alloc = [&](size_t bytes) -> char* {
        char* p = ws + o;
        o = (o + bytes + 255) & ~(size_t)255;
        return p;
    };
    bf16_t*   ha    = (bf16_t*)alloc((size_t)N * 256 * 2);  // [x | agg], later t2
    bf16_t*   hb    = (bf16_t*)alloc((size_t)N * 256 * 2);  // t1
    bf16_t*   wcb   = (bf16_t*)alloc((size_t)256 * 256 * 2);
    bf16_t*   w2b   = (bf16_t*)alloc((size_t)256 * 256 * 2);
    bf16_t*   w3b   = (bf16_t*)alloc((size_t)128 * 256 * 2);
    float*    bcomb = (float*)alloc(256 * 4);
    float*    stats = (float*)alloc(4 * 256 * 4);   // sum1, sq1, sum2, sq2
    float2*   scsh1 = (float2*)alloc(256 * 8);
    float2*   scsh2 = (float2*)alloc(256 * 8);
    int*      bcnt  = (int*)alloc(1024 * 4);
    int*      boffs = (int*)alloc(1025 * 4);
    int*      gcur  = (int*)alloc(1024 * 4);
    int*      offs  = (int*)alloc((size_t)(N + 1) * 4);
    unsigned* pairs = (unsigned*)alloc((size_t)E * 4);
    int*      csr   = (int*)alloc((size_t)E * 4);
    int*      flag  = (int*)alloc(4);

    const int NBK = (N + 127) >> 7;

    hipMemsetAsync(bcnt, 0, 1024 * 4, stream);
    hipMemsetAsync(stats, 0, 4 * 256 * 4, stream);
    hipMemsetAsync(flag, 0, 4, stream);

    // conversions / weight prep
    int nx8 = N * 16;
    conv_x_k<<<(nx8 + 255) / 256, 256, 0, stream>>>(x, ha, nx8);
    wcomb_k<<<256, 256, 0, stream>>>(w1, lin_w, lin_b, eps, wcb, bcomb);
    conv_k<<<32, 256, 0, stream>>>(w2, w2b, 8192);
    conv_k<<<16, 256, 0, stream>>>(w3, w3b, 4096);

    // two-level bucket sort of edges -> per-node CSR (all writes coalesced)
    const int nch = (E + CHUNK - 1) / CHUNK;
    detect_k<<<1, 256, 0, stream>>>((const int*)ei, flag);
    bhist_k<<<nch, 256, 0, stream>>>(ei, flag, E, bcnt);
    bscan_k<<<1, 1024, 0, stream>>>(bcnt, boffs, gcur, offs, NBK, N, E);
    binfill_k<<<nch, 256, 0, stream>>>(ei, flag, E, NBK, gcur, pairs);
    bsort2_k<<<NBK, 256, 0, stream>>>(pairs, boffs, offs, csr, N);
    gather_k<<<(N + 3) / 4, 256, 0, stream>>>(ha, offs, csr, N);

    const int nb = (N + 127) / 128;
    // t1 = [x|agg] @ Wc^T + bcomb (+ BN1 stats)
    gemm_k<256, false, true, false, true><<<nb, 512, 0, stream>>>(
        ha, wcb, nullptr, stats + 0, stats + 256, bcomb, hb, nullptr, N);
    finalize_k<<<1, 256, 0, stream>>>(stats + 0, stats + 256, g1, b1, scsh1, 1.f / (float)N);
    // t2 = relu(BN1(t1))@w2^T (+ BN2 stats)
    gemm_k<256, true, true, false, false><<<nb, 512, 0, stream>>>(
        hb, w2b, scsh1, stats + 512, stats + 768, nullptr, ha, nullptr, N);
    finalize_k<<<1, 256, 0, stream>>>(stats + 512, stats + 768, g2, b2, scsh2, 1.f / (float)N);
    // out = relu(BN2(t2))@w3^T + b3
    gemm_k<128, true, false, true, true><<<nb, 256, 0, stream>>>(
        ha, w3b, scsh2, nullptr, nullptr, b3, nullptr, out, N);
}